// Round 1
// baseline (367.647 us; speedup 1.0000x reference)
//
#include <hip/hip_runtime.h>

// Problem constants (fixed by the reference)
#define NB    2
#define LQT   12096      // query tokens per batch
#define LINT  2304       // feat tokens per batch (48*48)
#define DIMC  768
#define NHD   6
#define NPT   4
#define DHD   128
#define HIDC  192
#define HH    48
#define WW    48

typedef __attribute__((ext_vector_type(8))) short bf16x8;
typedef __attribute__((ext_vector_type(4))) float f32x4;
typedef __attribute__((ext_vector_type(8))) unsigned short u16x8;

__device__ __forceinline__ unsigned short f2bf(float f) {
  unsigned int u = __builtin_bit_cast(unsigned int, f);
  u += 0x7FFFu + ((u >> 16) & 1u);   // round-to-nearest-even
  return (unsigned short)(u >> 16);
}

// ---------------- weight packing: transpose [K][N]->bf16 [rows>=N][K], pad rows with 0
__global__ __launch_bounds__(256) void pack_wt(const float* __restrict__ src,
                                               unsigned short* __restrict__ dst,
                                               int K, int N, int rows) {
  size_t i = (size_t)blockIdx.x * 256 + threadIdx.x;
  if (i >= (size_t)rows * K) return;
  int n = (int)(i / K), k = (int)(i % K);
  float v = (n < N) ? src[(size_t)k * N + n] : 0.f;
  dst[i] = f2bf(v);
}

// fused sampling-offset (48 cols) + attn-weight (24 cols) weight pack into [128][768]
__global__ __launch_bounds__(256) void pack_soaw(const float* __restrict__ soW,
                                                 const float* __restrict__ awW,
                                                 const float* __restrict__ sob,
                                                 const float* __restrict__ awb,
                                                 unsigned short* __restrict__ dst,
                                                 float* __restrict__ bdst) {
  size_t i = (size_t)blockIdx.x * 256 + threadIdx.x;
  if (i < 128) bdst[i] = (i < 48) ? sob[i] : (i < 72 ? awb[i - 48] : 0.f);
  if (i >= (size_t)128 * DIMC) return;
  int n = (int)(i / DIMC), k = (int)(i % DIMC);
  float v = (n < 48) ? soW[(size_t)k * 48 + n]
                     : (n < 72 ? awW[(size_t)k * 24 + (n - 48)] : 0.f);
  dst[i] = f2bf(v);
}

// ---------------- LayerNorm (eps=1e-6) fp32 -> bf16, one row (768) per 256-thread block
__global__ __launch_bounds__(256) void ln_to_bf16(const float* __restrict__ in,
                                                  const float* __restrict__ gamma,
                                                  const float* __restrict__ beta,
                                                  unsigned short* __restrict__ out) {
  const int row = blockIdx.x;
  const int t = threadIdx.x;
  const float* x = in + (size_t)row * DIMC;
  float v0 = x[t], v1 = x[t + 256], v2 = x[t + 512];
  float s = v0 + v1 + v2;
  float s2 = v0 * v0 + v1 * v1 + v2 * v2;
#pragma unroll
  for (int o = 32; o > 0; o >>= 1) {
    s += __shfl_down(s, o);
    s2 += __shfl_down(s2, o);
  }
  __shared__ float red[8];
  const int wave = t >> 6, lane = t & 63;
  if (lane == 0) { red[wave] = s; red[wave + 4] = s2; }
  __syncthreads();
  float S = red[0] + red[1] + red[2] + red[3];
  float S2 = red[4] + red[5] + red[6] + red[7];
  float mean = S * (1.0f / DIMC);
  float var = S2 * (1.0f / DIMC) - mean * mean;
  float inv = rsqrtf(var + 1e-6f);
  unsigned short* o0 = out + (size_t)row * DIMC;
  o0[t]       = f2bf((v0 - mean) * inv * gamma[t]       + beta[t]);
  o0[t + 256] = f2bf((v1 - mean) * inv * gamma[t + 256] + beta[t + 256]);
  o0[t + 512] = f2bf((v2 - mean) * inv * gamma[t + 512] + beta[t + 512]);
}

// ---------------- bf16 MFMA GEMM: C[M][N] = A[M][K] * Bt[N][K]^T + bias (+ add)
// 128x128 tile, BK=32, 4 waves (2x2), each wave 4x4 frags of 16x16x32.
#define LDSS 40  // padded LDS row stride (ushorts): 2-way banks only
template <bool HAS_ADD>
__global__ __launch_bounds__(256) void gemm_bt(const unsigned short* __restrict__ A,
                                               const unsigned short* __restrict__ Bt,
                                               const float* __restrict__ bias,
                                               const float* __restrict__ add,
                                               float* __restrict__ out,
                                               int M, int N, int K) {
  __shared__ unsigned short As[128 * LDSS];
  __shared__ unsigned short Bs[128 * LDSS];
  const int t = threadIdx.x;
  const int wave = t >> 6, lane = t & 63;
  const int m0 = blockIdx.x * 128;
  const int n0 = blockIdx.y * 128;
  const int wm = (wave >> 1) * 64, wn = (wave & 1) * 64;
  const int lr = lane & 15;          // fragment row (A) / col (B)
  const int lk = (lane >> 4) * 8;    // fragment k offset (contiguous 8)

  const int e0 = t * 8;              // staging: each thread 2x 8-elem chunks
  const int r0 = e0 >> 5;            // 0..63
  const int c0 = e0 & 31;

  const size_t arow0 = (size_t)(m0 + r0) * K;
  const size_t arow1 = (size_t)(m0 + r0 + 64) * K;
  const size_t brow0 = (size_t)(n0 + r0) * K;
  const size_t brow1 = (size_t)(n0 + r0 + 64) * K;

  f32x4 acc[4][4] = {};

  for (int k0 = 0; k0 < K; k0 += 32) {
    u16x8 a0 = *(const u16x8*)(A + arow0 + k0 + c0);
    u16x8 a1 = *(const u16x8*)(A + arow1 + k0 + c0);
    u16x8 b0 = *(const u16x8*)(Bt + brow0 + k0 + c0);
    u16x8 b1 = *(const u16x8*)(Bt + brow1 + k0 + c0);
    __syncthreads();
    *(u16x8*)(As + (size_t)r0 * LDSS + c0) = a0;
    *(u16x8*)(As + (size_t)(r0 + 64) * LDSS + c0) = a1;
    *(u16x8*)(Bs + (size_t)r0 * LDSS + c0) = b0;
    *(u16x8*)(Bs + (size_t)(r0 + 64) * LDSS + c0) = b1;
    __syncthreads();
    bf16x8 af[4], bg[4];
#pragma unroll
    for (int i = 0; i < 4; ++i)
      af[i] = *(const bf16x8*)(As + (size_t)(wm + i * 16 + lr) * LDSS + lk);
#pragma unroll
    for (int j = 0; j < 4; ++j)
      bg[j] = *(const bf16x8*)(Bs + (size_t)(wn + j * 16 + lr) * LDSS + lk);
#pragma unroll
    for (int i = 0; i < 4; ++i)
#pragma unroll
      for (int j = 0; j < 4; ++j)
        acc[i][j] = __builtin_amdgcn_mfma_f32_16x16x32_bf16(af[i], bg[j], acc[i][j], 0, 0, 0);
  }

  const int orow = (lane >> 4) * 4;
#pragma unroll
  for (int i = 0; i < 4; ++i) {
#pragma unroll
    for (int j = 0; j < 4; ++j) {
      const int n = n0 + wn + j * 16 + lr;
      if (n < N) {
#pragma unroll
        for (int r = 0; r < 4; ++r) {
          const int m = m0 + wm + i * 16 + orow + r;
          float v = acc[i][j][r] + bias[n];
          if (HAS_ADD) v += add[(size_t)m * N + n];
          out[(size_t)m * N + n] = v;
        }
      }
    }
  }
}

// ---------------- deformable sampling: softmax(attw) + bilinear gather + NP-sum
// grid = NB*LQT blocks, block = 192 threads: head = t>>5, 32 lanes x float4 over DH=128
__global__ __launch_bounds__(192) void deform_attn(const float* __restrict__ soaw,
                                                   const float* __restrict__ rp,
                                                   const float* __restrict__ value,
                                                   unsigned short* __restrict__ attn) {
  const int row = blockIdx.x;  // b*LQT + q
  const int b = row / LQT;
  const int t = threadIdx.x;
  const int h = t >> 5;
  const int l = t & 31;
  const float* sa = soaw + (size_t)row * 128;
  const float bx = rp[(size_t)row * 2 + 0] * (float)WW - 0.5f;
  const float by = rp[(size_t)row * 2 + 1] * (float)HH - 0.5f;

  // softmax over NP=4 attention logits of this head
  float lg0 = sa[48 + h * 4 + 0], lg1 = sa[48 + h * 4 + 1];
  float lg2 = sa[48 + h * 4 + 2], lg3 = sa[48 + h * 4 + 3];
  float mx = fmaxf(fmaxf(lg0, lg1), fmaxf(lg2, lg3));
  float e0 = expf(lg0 - mx), e1 = expf(lg1 - mx), e2 = expf(lg2 - mx), e3 = expf(lg3 - mx);
  float inv = 1.0f / (e0 + e1 + e2 + e3);
  float awp[4] = {e0 * inv, e1 * inv, e2 * inv, e3 * inv};

  const float* vb = value + (size_t)b * LINT * DIMC + h * DHD + l * 4;
  float ax = 0.f, ay = 0.f, az = 0.f, aw = 0.f;
#pragma unroll
  for (int p = 0; p < 4; ++p) {
    float fx = bx + sa[h * 8 + p * 2 + 0];
    float fy = by + sa[h * 8 + p * 2 + 1];
    float x0f = floorf(fx), y0f = floorf(fy);
    float wx = fx - x0f, wy = fy - y0f;
    int x0 = (int)x0f, y0 = (int)y0f;
#pragma unroll
    for (int dy = 0; dy < 2; ++dy) {
#pragma unroll
      for (int dx = 0; dx < 2; ++dx) {
        int xi = x0 + dx, yi = y0 + dy;
        float w = (dy ? wy : 1.f - wy) * (dx ? wx : 1.f - wx) * awp[p];
        if (xi < 0 || xi >= WW || yi < 0 || yi >= HH) w = 0.f;
        int xc = min(max(xi, 0), WW - 1), yc = min(max(yi, 0), HH - 1);
        const float4 g = *(const float4*)(vb + (size_t)(yc * WW + xc) * DIMC);
        ax += w * g.x; ay += w * g.y; az += w * g.z; aw += w * g.w;
      }
    }
  }
  unsigned short* op = attn + (size_t)row * DIMC + h * DHD + l * 4;
  ushort4 ov;
  ov.x = f2bf(ax); ov.y = f2bf(ay); ov.z = f2bf(az); ov.w = f2bf(aw);
  *(ushort4*)op = ov;
}

// ---------------- depthwise 3x3 conv (3 image scales) + exact GELU -> bf16
__global__ __launch_bounds__(192) void dwconv_gelu(const float* __restrict__ h1,
                                                   const float* __restrict__ dwW,
                                                   const float* __restrict__ dwb,
                                                   unsigned short* __restrict__ out) {
  const int blk = blockIdx.x;  // b*LQT + q
  const int b = blk / LQT;
  const int q = blk % LQT;
  int base, Wi, Hi;
  if (q < 9216)       { base = 0;     Wi = 96; Hi = 96; }
  else if (q < 11520) { base = 9216;  Wi = 48; Hi = 48; }
  else                { base = 11520; Wi = 24; Hi = 24; }
  const int loc = q - base;
  const int y = loc / Wi, x = loc % Wi;
  const int c = threadIdx.x;
  const float* src = h1 + ((size_t)b * LQT + base) * HIDC + c;
  float acc = dwb[c];
#pragma unroll
  for (int dy = -1; dy <= 1; ++dy) {
    int yy = y + dy;
    if (yy < 0 || yy >= Hi) continue;
#pragma unroll
    for (int dx = -1; dx <= 1; ++dx) {
      int xx = x + dx;
      if (xx < 0 || xx >= Wi) continue;
      acc += dwW[c * 9 + (dy + 1) * 3 + (dx + 1)] * src[(size_t)(yy * Wi + xx) * HIDC];
    }
  }
  float g = 0.5f * acc * (1.0f + erff(acc * 0.70710678118654752f));
  out[(size_t)blk * HIDC + c] = f2bf(g);
}

// ---------------- launch
extern "C" void kernel_launch(void* const* d_in, const int* in_sizes, int n_in,
                              void* d_out, int out_size, void* d_ws, size_t ws_size,
                              hipStream_t stream) {
  const float* query = (const float*)d_in[0];
  const float* rp    = (const float*)d_in[1];
  const float* feat  = (const float*)d_in[2];
  const float* qn_g  = (const float*)d_in[7];
  const float* qn_b  = (const float*)d_in[8];
  const float* fn_g  = (const float*)d_in[9];
  const float* fn_b  = (const float*)d_in[10];
  const float* mn_g  = (const float*)d_in[11];
  const float* mn_b  = (const float*)d_in[12];
  const float* vW    = (const float*)d_in[13];
  const float* vb    = (const float*)d_in[14];
  const float* soW   = (const float*)d_in[15];
  const float* sob   = (const float*)d_in[16];
  const float* awW   = (const float*)d_in[17];
  const float* awb   = (const float*)d_in[18];
  const float* opW   = (const float*)d_in[19];
  const float* opb   = (const float*)d_in[20];
  const float* fc1W  = (const float*)d_in[21];
  const float* fc1b  = (const float*)d_in[22];
  const float* dwW   = (const float*)d_in[23];
  const float* dwb   = (const float*)d_in[24];
  const float* fc2W  = (const float*)d_in[25];
  const float* fc2b  = (const float*)d_in[26];
  float* out = (float*)d_out;
  (void)in_sizes; (void)n_in; (void)out_size; (void)ws_size;

  char* ws = (char*)d_ws;
  size_t off = 0;
  auto alloc = [&](size_t bytes) -> void* {
    off = (off + 255) & ~(size_t)255;
    void* p = ws + off;
    off += bytes;
    return p;
  };

  const int MQ = NB * LQT;   // 24192
  const int MF = NB * LINT;  // 4608

  unsigned short* vWt    = (unsigned short*)alloc((size_t)768 * 768 * 2);
  unsigned short* opWt   = (unsigned short*)alloc((size_t)768 * 768 * 2);
  unsigned short* soawWt = (unsigned short*)alloc((size_t)128 * 768 * 2);
  unsigned short* fc1Wt  = (unsigned short*)alloc((size_t)256 * 768 * 2);
  unsigned short* fc2Wt  = (unsigned short*)alloc((size_t)768 * 192 * 2);
  float*          soawb  = (float*)alloc(128 * 4);
  unsigned short* f_ln   = (unsigned short*)alloc((size_t)MF * DIMC * 2);
  unsigned short* q_ln   = (unsigned short*)alloc((size_t)MQ * DIMC * 2);  // reused as ln(x)
  float*          value  = (float*)alloc((size_t)MF * DIMC * 4);
  float*          soaw   = (float*)alloc((size_t)MQ * 128 * 4);            // reused as conv out (bf16)
  unsigned short* attnb  = (unsigned short*)alloc((size_t)MQ * DIMC * 2);  // reused as h1 (fp32, 18.6MB<37.2MB)
  float*          xbuf   = (float*)alloc((size_t)MQ * DIMC * 4);

  float* h1 = (float*)attnb;
  unsigned short* coutb = (unsigned short*)soaw;
  unsigned short* lnx = q_ln;

  // weight packing (tiny)
  pack_wt<<<dim3((768 * 768 + 255) / 256), dim3(256), 0, stream>>>(vW, vWt, 768, 768, 768);
  pack_wt<<<dim3((768 * 768 + 255) / 256), dim3(256), 0, stream>>>(opW, opWt, 768, 768, 768);
  pack_wt<<<dim3((256 * 768 + 255) / 256), dim3(256), 0, stream>>>(fc1W, fc1Wt, 768, 192, 256);
  pack_wt<<<dim3((768 * 192 + 255) / 256), dim3(256), 0, stream>>>(fc2W, fc2Wt, 192, 768, 768);
  pack_soaw<<<dim3((128 * 768 + 255) / 256), dim3(256), 0, stream>>>(soW, awW, sob, awb, soawWt, soawb);

  // LayerNorms
  ln_to_bf16<<<dim3(MF), dim3(256), 0, stream>>>(feat, fn_g, fn_b, f_ln);
  ln_to_bf16<<<dim3(MQ), dim3(256), 0, stream>>>(query, qn_g, qn_b, q_ln);

  // value projection: [4608,768] = f_ln @ vW + vb
  gemm_bt<false><<<dim3(MF / 128, 6), dim3(256), 0, stream>>>(f_ln, vWt, vb, nullptr, value, MF, 768, 768);

  // sampling offsets + attn logits (fused, N=128 padded)
  gemm_bt<false><<<dim3(MQ / 128, 1), dim3(256), 0, stream>>>(q_ln, soawWt, soawb, nullptr, soaw, MQ, 128, 768);

  // deformable bilinear sampling -> attn operand (bf16)
  deform_attn<<<dim3(MQ), dim3(192), 0, stream>>>(soaw, rp, value, attnb);

  // output projection + residual: x = attn @ opW + opb + query
  gemm_bt<true><<<dim3(MQ / 128, 6), dim3(256), 0, stream>>>(attnb, opWt, opb, query, xbuf, MQ, 768, 768);

  // LN(x)
  ln_to_bf16<<<dim3(MQ), dim3(256), 0, stream>>>(xbuf, mn_g, mn_b, lnx);

  // fc1: [MQ,192] = lnx @ fc1W + fc1b
  gemm_bt<false><<<dim3(MQ / 128, 2), dim3(256), 0, stream>>>(lnx, fc1Wt, fc1b, nullptr, h1, MQ, 192, 768);

  // depthwise conv (3 scales) + GELU
  dwconv_gelu<<<dim3(MQ), dim3(192), 0, stream>>>(h1, dwW, dwb, coutb);

  // fc2 + residual: out = x + cout @ fc2W + fc2b
  gemm_bt<true><<<dim3(MQ / 128, 6), dim3(256), 0, stream>>>(coutb, fc2Wt, fc2b, xbuf, out, MQ, 768, 192);
}

// Round 2
// 346.929 us; speedup vs baseline: 1.0597x; 1.0597x over previous
//
#include <hip/hip_runtime.h>

// Problem constants (fixed by the reference)
#define NB    2
#define LQT   12096      // query tokens per batch
#define LINT  2304       // feat tokens per batch (48*48)
#define DIMC  768
#define NHD   6
#define NPT   4
#define DHD   128
#define HIDC  192
#define HH    48
#define WW    48

typedef __attribute__((ext_vector_type(8))) short bf16x8;
typedef __attribute__((ext_vector_type(4))) float f32x4;
typedef __attribute__((ext_vector_type(8))) unsigned short u16x8;

__device__ __forceinline__ unsigned short f2bf(float f) {
  unsigned int u = __builtin_bit_cast(unsigned int, f);
  u += 0x7FFFu + ((u >> 16) & 1u);   // round-to-nearest-even
  return (unsigned short)(u >> 16);
}

// global -> LDS direct copy, 16B per lane. LDS base must be wave-uniform.
__device__ __forceinline__ void gload16(const unsigned short* g, unsigned short* l) {
  __builtin_amdgcn_global_load_lds(
      (const __attribute__((address_space(1))) unsigned int*)g,
      (__attribute__((address_space(3))) unsigned int*)l, 16, 0, 0);
}

// ---------------- weight packing: transpose [K][N]->bf16 [rows>=N][K], pad rows with 0
__global__ __launch_bounds__(256) void pack_wt(const float* __restrict__ src,
                                               unsigned short* __restrict__ dst,
                                               int K, int N, int rows) {
  size_t i = (size_t)blockIdx.x * 256 + threadIdx.x;
  if (i >= (size_t)rows * K) return;
  int n = (int)(i / K), k = (int)(i % K);
  float v = (n < N) ? src[(size_t)k * N + n] : 0.f;
  dst[i] = f2bf(v);
}

// fused sampling-offset (48 cols) + attn-weight (24 cols) weight pack into [128][768]
__global__ __launch_bounds__(256) void pack_soaw(const float* __restrict__ soW,
                                                 const float* __restrict__ awW,
                                                 const float* __restrict__ sob,
                                                 const float* __restrict__ awb,
                                                 unsigned short* __restrict__ dst,
                                                 float* __restrict__ bdst) {
  size_t i = (size_t)blockIdx.x * 256 + threadIdx.x;
  if (i < 128) bdst[i] = (i < 48) ? sob[i] : (i < 72 ? awb[i - 48] : 0.f);
  if (i >= (size_t)128 * DIMC) return;
  int n = (int)(i / DIMC), k = (int)(i % DIMC);
  float v = (n < 48) ? soW[(size_t)k * 48 + n]
                     : (n < 72 ? awW[(size_t)k * 24 + (n - 48)] : 0.f);
  dst[i] = f2bf(v);
}

// ---------------- LayerNorm (eps=1e-6) fp32 -> bf16, one row (768) per 256-thread block
__global__ __launch_bounds__(256) void ln_to_bf16(const float* __restrict__ in,
                                                  const float* __restrict__ gamma,
                                                  const float* __restrict__ beta,
                                                  unsigned short* __restrict__ out) {
  const int row = blockIdx.x;
  const int t = threadIdx.x;
  const float* x = in + (size_t)row * DIMC;
  float v0 = x[t], v1 = x[t + 256], v2 = x[t + 512];
  float s = v0 + v1 + v2;
  float s2 = v0 * v0 + v1 * v1 + v2 * v2;
#pragma unroll
  for (int o = 32; o > 0; o >>= 1) {
    s += __shfl_down(s, o);
    s2 += __shfl_down(s2, o);
  }
  __shared__ float red[8];
  const int wave = t >> 6, lane = t & 63;
  if (lane == 0) { red[wave] = s; red[wave + 4] = s2; }
  __syncthreads();
  float S = red[0] + red[1] + red[2] + red[3];
  float S2 = red[4] + red[5] + red[6] + red[7];
  float mean = S * (1.0f / DIMC);
  float var = S2 * (1.0f / DIMC) - mean * mean;
  float inv = rsqrtf(var + 1e-6f);
  unsigned short* o0 = out + (size_t)row * DIMC;
  o0[t]       = f2bf((v0 - mean) * inv * gamma[t]       + beta[t]);
  o0[t + 256] = f2bf((v1 - mean) * inv * gamma[t + 256] + beta[t + 256]);
  o0[t + 512] = f2bf((v2 - mean) * inv * gamma[t + 512] + beta[t + 512]);
}

// ---------------- bf16 MFMA GEMM: C[M][N] = A[M][K] * Bt[N][K]^T + bias (+ add)
// 128x128 tile, BK=64, 4 waves (2x2), each wave 4x4 frags of 16x16x32.
// global_load_lds(16B) staging into linear LDS [128 rows][8 slots of 16B];
// XOR swizzle slot^(row&7) applied on BOTH the per-lane global source address
// and the ds_read address (rule: both-sides-or-neither).
template <bool HAS_ADD>
__global__ __launch_bounds__(256) void gemm_bt(const unsigned short* __restrict__ A,
                                               const unsigned short* __restrict__ Bt,
                                               const float* __restrict__ bias,
                                               const float* __restrict__ add,
                                               float* __restrict__ out,
                                               int M, int N, int K) {
  __shared__ unsigned short As[128 * 64];
  __shared__ unsigned short Bs[128 * 64];
  const int t = threadIdx.x;
  const int wave = t >> 6, lane = t & 63;
  const int m0 = blockIdx.x * 128;
  const int n0 = blockIdx.y * 128;
  const int wm = (wave >> 1) * 64, wn = (wave & 1) * 64;
  const int lr = lane & 15;          // fragment row (A) / col (B)
  const int lg = lane >> 4;          // k-group 0..3 (8 ushorts each)

  // staging geometry: wave covers rows wave*32 .. wave*32+31 (4 issues of 8 rows)
  const int srow = wave * 32 + (lane >> 3);  // + i*8
  const int sslot = lane & 7;

  f32x4 acc[4][4] = {};

  for (int k0 = 0; k0 < K; k0 += 64) {
    __syncthreads();   // previous iter's LDS reads done before overwrite
#pragma unroll
    for (int i = 0; i < 4; ++i) {
      const int row = srow + i * 8;
      const int ca = sslot ^ (row & 7);          // pre-swizzled source chunk
      gload16(A  + (size_t)(m0 + row) * K + k0 + ca * 8, As + (wave * 32 + i * 8) * 64);
      gload16(Bt + (size_t)(n0 + row) * K + k0 + ca * 8, Bs + (wave * 32 + i * 8) * 64);
    }
    __syncthreads();   // compiler drains vmcnt before barrier -> tiles visible

    bf16x8 af[2][4], bg[2][4];
#pragma unroll
    for (int kk = 0; kk < 2; ++kk) {
#pragma unroll
      for (int i = 0; i < 4; ++i) {
        int row = wm + i * 16 + lr;
        int slot = (kk * 4 + lg) ^ (row & 7);
        af[kk][i] = *(const bf16x8*)(As + row * 64 + slot * 8);
        row = wn + i * 16 + lr;
        slot = (kk * 4 + lg) ^ (row & 7);
        bg[kk][i] = *(const bf16x8*)(Bs + row * 64 + slot * 8);
      }
    }
#pragma unroll
    for (int kk = 0; kk < 2; ++kk)
#pragma unroll
      for (int i = 0; i < 4; ++i)
#pragma unroll
        for (int j = 0; j < 4; ++j)
          acc[i][j] = __builtin_amdgcn_mfma_f32_16x16x32_bf16(af[kk][i], bg[kk][j], acc[i][j], 0, 0, 0);
  }

  const int orow = lg * 4;
#pragma unroll
  for (int i = 0; i < 4; ++i) {
#pragma unroll
    for (int j = 0; j < 4; ++j) {
      const int n = n0 + wn + j * 16 + lr;
      if (n < N) {
#pragma unroll
        for (int r = 0; r < 4; ++r) {
          const int m = m0 + wm + i * 16 + orow + r;
          float v = acc[i][j][r] + bias[n];
          if (HAS_ADD) v += add[(size_t)m * N + n];
          out[(size_t)m * N + n] = v;
        }
      }
    }
  }
}

// ---------------- deformable sampling: softmax(attw) + bilinear gather + NP-sum
// grid = NB*LQT blocks, block = 192 threads: head = t>>5, 32 lanes x float4 over DH=128
__global__ __launch_bounds__(192) void deform_attn(const float* __restrict__ soaw,
                                                   const float* __restrict__ rp,
                                                   const float* __restrict__ value,
                                                   unsigned short* __restrict__ attn) {
  const int row = blockIdx.x;  // b*LQT + q
  const int b = row / LQT;
  const int t = threadIdx.x;
  const int h = t >> 5;
  const int l = t & 31;
  const float* sa = soaw + (size_t)row * 128;
  const float bx = rp[(size_t)row * 2 + 0] * (float)WW - 0.5f;
  const float by = rp[(size_t)row * 2 + 1] * (float)HH - 0.5f;

  // softmax over NP=4 attention logits of this head
  float lg0 = sa[48 + h * 4 + 0], lg1 = sa[48 + h * 4 + 1];
  float lg2 = sa[48 + h * 4 + 2], lg3 = sa[48 + h * 4 + 3];
  float mx = fmaxf(fmaxf(lg0, lg1), fmaxf(lg2, lg3));
  float e0 = expf(lg0 - mx), e1 = expf(lg1 - mx), e2 = expf(lg2 - mx), e3 = expf(lg3 - mx);
  float inv = 1.0f / (e0 + e1 + e2 + e3);
  float awp[4] = {e0 * inv, e1 * inv, e2 * inv, e3 * inv};

  const float* vb = value + (size_t)b * LINT * DIMC + h * DHD + l * 4;
  float ax = 0.f, ay = 0.f, az = 0.f, aw = 0.f;
#pragma unroll
  for (int p = 0; p < 4; ++p) {
    float fx = bx + sa[h * 8 + p * 2 + 0];
    float fy = by + sa[h * 8 + p * 2 + 1];
    float x0f = floorf(fx), y0f = floorf(fy);
    float wx = fx - x0f, wy = fy - y0f;
    int x0 = (int)x0f, y0 = (int)y0f;
#pragma unroll
    for (int dy = 0; dy < 2; ++dy) {
#pragma unroll
      for (int dx = 0; dx < 2; ++dx) {
        int xi = x0 + dx, yi = y0 + dy;
        float w = (dy ? wy : 1.f - wy) * (dx ? wx : 1.f - wx) * awp[p];
        if (xi < 0 || xi >= WW || yi < 0 || yi >= HH) w = 0.f;
        int xc = min(max(xi, 0), WW - 1), yc = min(max(yi, 0), HH - 1);
        const float4 g = *(const float4*)(vb + (size_t)(yc * WW + xc) * DIMC);
        ax += w * g.x; ay += w * g.y; az += w * g.z; aw += w * g.w;
      }
    }
  }
  unsigned short* op = attn + (size_t)row * DIMC + h * DHD + l * 4;
  ushort4 ov;
  ov.x = f2bf(ax); ov.y = f2bf(ay); ov.z = f2bf(az); ov.w = f2bf(aw);
  *(ushort4*)op = ov;
}

// ---------------- depthwise 3x3 conv (3 image scales) + exact GELU -> bf16
__global__ __launch_bounds__(192) void dwconv_gelu(const float* __restrict__ h1,
                                                   const float* __restrict__ dwW,
                                                   const float* __restrict__ dwb,
                                                   unsigned short* __restrict__ out) {
  const int blk = blockIdx.x;  // b*LQT + q
  const int b = blk / LQT;
  const int q = blk % LQT;
  int base, Wi, Hi;
  if (q < 9216)       { base = 0;     Wi = 96; Hi = 96; }
  else if (q < 11520) { base = 9216;  Wi = 48; Hi = 48; }
  else                { base = 11520; Wi = 24; Hi = 24; }
  const int loc = q - base;
  const int y = loc / Wi, x = loc % Wi;
  const int c = threadIdx.x;
  const float* src = h1 + ((size_t)b * LQT + base) * HIDC + c;
  float acc = dwb[c];
#pragma unroll
  for (int dy = -1; dy <= 1; ++dy) {
    int yy = y + dy;
    if (yy < 0 || yy >= Hi) continue;
#pragma unroll
    for (int dx = -1; dx <= 1; ++dx) {
      int xx = x + dx;
      if (xx < 0 || xx >= Wi) continue;
      acc += dwW[c * 9 + (dy + 1) * 3 + (dx + 1)] * src[(size_t)(yy * Wi + xx) * HIDC];
    }
  }
  float g = 0.5f * acc * (1.0f + erff(acc * 0.70710678118654752f));
  out[(size_t)blk * HIDC + c] = f2bf(g);
}

// ---------------- launch
extern "C" void kernel_launch(void* const* d_in, const int* in_sizes, int n_in,
                              void* d_out, int out_size, void* d_ws, size_t ws_size,
                              hipStream_t stream) {
  const float* query = (const float*)d_in[0];
  const float* rp    = (const float*)d_in[1];
  const float* feat  = (const float*)d_in[2];
  const float* qn_g  = (const float*)d_in[7];
  const float* qn_b  = (const float*)d_in[8];
  const float* fn_g  = (const float*)d_in[9];
  const float* fn_b  = (const float*)d_in[10];
  const float* mn_g  = (const float*)d_in[11];
  const float* mn_b  = (const float*)d_in[12];
  const float* vW    = (const float*)d_in[13];
  const float* vb    = (const float*)d_in[14];
  const float* soW   = (const float*)d_in[15];
  const float* sob   = (const float*)d_in[16];
  const float* awW   = (const float*)d_in[17];
  const float* awb   = (const float*)d_in[18];
  const float* opW   = (const float*)d_in[19];
  const float* opb   = (const float*)d_in[20];
  const float* fc1W  = (const float*)d_in[21];
  const float* fc1b  = (const float*)d_in[22];
  const float* dwW   = (const float*)d_in[23];
  const float* dwb   = (const float*)d_in[24];
  const float* fc2W  = (const float*)d_in[25];
  const float* fc2b  = (const float*)d_in[26];
  float* out = (float*)d_out;
  (void)in_sizes; (void)n_in; (void)out_size; (void)ws_size;

  char* ws = (char*)d_ws;
  size_t off = 0;
  auto alloc = [&](size_t bytes) -> void* {
    off = (off + 255) & ~(size_t)255;
    void* p = ws + off;
    off += bytes;
    return p;
  };

  const int MQ = NB * LQT;   // 24192
  const int MF = NB * LINT;  // 4608

  unsigned short* vWt    = (unsigned short*)alloc((size_t)768 * 768 * 2);
  unsigned short* opWt   = (unsigned short*)alloc((size_t)768 * 768 * 2);
  unsigned short* soawWt = (unsigned short*)alloc((size_t)128 * 768 * 2);
  unsigned short* fc1Wt  = (unsigned short*)alloc((size_t)256 * 768 * 2);
  unsigned short* fc2Wt  = (unsigned short*)alloc((size_t)768 * 192 * 2);
  float*          soawb  = (float*)alloc(128 * 4);
  unsigned short* f_ln   = (unsigned short*)alloc((size_t)MF * DIMC * 2);
  unsigned short* q_ln   = (unsigned short*)alloc((size_t)MQ * DIMC * 2);  // reused as ln(x)
  float*          value  = (float*)alloc((size_t)MF * DIMC * 4);
  float*          soaw   = (float*)alloc((size_t)MQ * 128 * 4);            // reused as conv out (bf16)
  unsigned short* attnb  = (unsigned short*)alloc((size_t)MQ * DIMC * 2);  // reused as h1 (fp32 fits)
  float*          xbuf   = (float*)alloc((size_t)MQ * DIMC * 4);

  float* h1 = (float*)attnb;
  unsigned short* coutb = (unsigned short*)soaw;
  unsigned short* lnx = q_ln;

  // weight packing (tiny)
  pack_wt<<<dim3((768 * 768 + 255) / 256), dim3(256), 0, stream>>>(vW, vWt, 768, 768, 768);
  pack_wt<<<dim3((768 * 768 + 255) / 256), dim3(256), 0, stream>>>(opW, opWt, 768, 768, 768);
  pack_wt<<<dim3((256 * 768 + 255) / 256), dim3(256), 0, stream>>>(fc1W, fc1Wt, 768, 192, 256);
  pack_wt<<<dim3((768 * 192 + 255) / 256), dim3(256), 0, stream>>>(fc2W, fc2Wt, 192, 768, 768);
  pack_soaw<<<dim3((128 * 768 + 255) / 256), dim3(256), 0, stream>>>(soW, awW, sob, awb, soawWt, soawb);

  // LayerNorms
  ln_to_bf16<<<dim3(MF), dim3(256), 0, stream>>>(feat, fn_g, fn_b, f_ln);
  ln_to_bf16<<<dim3(MQ), dim3(256), 0, stream>>>(query, qn_g, qn_b, q_ln);

  // value projection: [4608,768] = f_ln @ vW + vb
  gemm_bt<false><<<dim3(MF / 128, 6), dim3(256), 0, stream>>>(f_ln, vWt, vb, nullptr, value, MF, 768, 768);

  // sampling offsets + attn logits (fused, N=128 padded)
  gemm_bt<false><<<dim3(MQ / 128, 1), dim3(256), 0, stream>>>(q_ln, soawWt, soawb, nullptr, soaw, MQ, 128, 768);

  // deformable bilinear sampling -> attn operand (bf16)
  deform_attn<<<dim3(MQ), dim3(192), 0, stream>>>(soaw, rp, value, attnb);

  // output projection + residual: x = attn @ opW + opb + query
  gemm_bt<true><<<dim3(MQ / 128, 6), dim3(256), 0, stream>>>(attnb, opWt, opb, query, xbuf, MQ, 768, 768);

  // LN(x)
  ln_to_bf16<<<dim3(MQ), dim3(256), 0, stream>>>(xbuf, mn_g, mn_b, lnx);

  // fc1: [MQ,192] = lnx @ fc1W + fc1b
  gemm_bt<false><<<dim3(MQ / 128, 2), dim3(256), 0, stream>>>(lnx, fc1Wt, fc1b, nullptr, h1, MQ, 192, 768);

  // depthwise conv (3 scales) + GELU
  dwconv_gelu<<<dim3(MQ), dim3(192), 0, stream>>>(h1, dwW, dwb, coutb);

  // fc2 + residual: out = x + cout @ fc2W + fc2b
  gemm_bt<true><<<dim3(MQ / 128, 6), dim3(256), 0, stream>>>(coutb, fc2Wt, fc2b, xbuf, out, MQ, 768, 192);
}

// Round 3
// 336.051 us; speedup vs baseline: 1.0940x; 1.0324x over previous
//
#include <hip/hip_runtime.h>

// Problem constants (fixed by the reference)
#define NB    2
#define LQT   12096      // query tokens per batch
#define LINT  2304       // feat tokens per batch (48*48)
#define DIMC  768
#define NHD   6
#define NPT   4
#define DHD   128
#define HIDC  192
#define HH    48
#define WW    48

typedef __attribute__((ext_vector_type(8))) short bf16x8;
typedef __attribute__((ext_vector_type(4))) float f32x4;
typedef __attribute__((ext_vector_type(8))) unsigned short u16x8;

__device__ __forceinline__ unsigned short f2bf(float f) {
  unsigned int u = __builtin_bit_cast(unsigned int, f);
  u += 0x7FFFu + ((u >> 16) & 1u);   // round-to-nearest-even
  return (unsigned short)(u >> 16);
}

// global -> LDS direct copy, 16B per lane. LDS base must be wave-uniform.
__device__ __forceinline__ void gload16(const unsigned short* g, unsigned short* l) {
  __builtin_amdgcn_global_load_lds(
      (const __attribute__((address_space(1))) unsigned int*)g,
      (__attribute__((address_space(3))) unsigned int*)l, 16, 0, 0);
}

// ---------------- weight packing: transpose [K][N]->bf16 [rows>=N][K], pad rows with 0
__global__ __launch_bounds__(256) void pack_wt(const float* __restrict__ src,
                                               unsigned short* __restrict__ dst,
                                               int K, int N, int rows) {
  size_t i = (size_t)blockIdx.x * 256 + threadIdx.x;
  if (i >= (size_t)rows * K) return;
  int n = (int)(i / K), k = (int)(i % K);
  float v = (n < N) ? src[(size_t)k * N + n] : 0.f;
  dst[i] = f2bf(v);
}

// fused sampling-offset (48 cols) + attn-weight (24 cols) weight pack into [128][768]
__global__ __launch_bounds__(256) void pack_soaw(const float* __restrict__ soW,
                                                 const float* __restrict__ awW,
                                                 const float* __restrict__ sob,
                                                 const float* __restrict__ awb,
                                                 unsigned short* __restrict__ dst,
                                                 float* __restrict__ bdst) {
  size_t i = (size_t)blockIdx.x * 256 + threadIdx.x;
  if (i < 128) bdst[i] = (i < 48) ? sob[i] : (i < 72 ? awb[i - 48] : 0.f);
  if (i >= (size_t)128 * DIMC) return;
  int n = (int)(i / DIMC), k = (int)(i % DIMC);
  float v = (n < 48) ? soW[(size_t)k * 48 + n]
                     : (n < 72 ? awW[(size_t)k * 24 + (n - 48)] : 0.f);
  dst[i] = f2bf(v);
}

// ---------------- LayerNorm (eps=1e-6) fp32 -> bf16, one row (768) per 256-thread block
__global__ __launch_bounds__(256) void ln_to_bf16(const float* __restrict__ in,
                                                  const float* __restrict__ gamma,
                                                  const float* __restrict__ beta,
                                                  unsigned short* __restrict__ out) {
  const int row = blockIdx.x;
  const int t = threadIdx.x;
  const float* x = in + (size_t)row * DIMC;
  float v0 = x[t], v1 = x[t + 256], v2 = x[t + 512];
  float s = v0 + v1 + v2;
  float s2 = v0 * v0 + v1 * v1 + v2 * v2;
#pragma unroll
  for (int o = 32; o > 0; o >>= 1) {
    s += __shfl_down(s, o);
    s2 += __shfl_down(s2, o);
  }
  __shared__ float red[8];
  const int wave = t >> 6, lane = t & 63;
  if (lane == 0) { red[wave] = s; red[wave + 4] = s2; }
  __syncthreads();
  float S = red[0] + red[1] + red[2] + red[3];
  float S2 = red[4] + red[5] + red[6] + red[7];
  float mean = S * (1.0f / DIMC);
  float var = S2 * (1.0f / DIMC) - mean * mean;
  float inv = rsqrtf(var + 1e-6f);
  unsigned short* o0 = out + (size_t)row * DIMC;
  o0[t]       = f2bf((v0 - mean) * inv * gamma[t]       + beta[t]);
  o0[t + 256] = f2bf((v1 - mean) * inv * gamma[t + 256] + beta[t + 256]);
  o0[t + 512] = f2bf((v2 - mean) * inv * gamma[t + 512] + beta[t + 512]);
}

// ---------------- bf16 MFMA GEMM: C[M][N] = A[M][K] * Bt[N][K]^T + bias (+ add)
// 128x128 tile, BK=64, 4 waves (2x2), each wave 4x4 frags of 16x16x32.
// Double-buffered LDS + prefetch-before-compute (T3 minimum 2-phase recipe):
//   stage(buf0); barrier; loop { stage(buf^1,next); ds_read+MFMA(buf); barrier; }
// 1-D grid, n-fastest linear id, bijective XCD-chunked swizzle (m204) so the
// n-sweep over one A-tile stays on one XCD's L2.
template <bool HAS_ADD>
__global__ __launch_bounds__(256) void gemm_bt(const unsigned short* __restrict__ A,
                                               const unsigned short* __restrict__ Bt,
                                               const float* __restrict__ bias,
                                               const float* __restrict__ add,
                                               float* __restrict__ out,
                                               int M, int N, int K, int nn) {
  __shared__ unsigned short As[2][128 * 64];
  __shared__ unsigned short Bs[2][128 * 64];
  const int t = threadIdx.x;
  const int wave = t >> 6, lane = t & 63;

  // bijective XCD-chunked swizzle (round-robin dispatch -> contiguous per-XCD chunk)
  const int nwg = gridDim.x;
  const int qq = nwg >> 3, rr = nwg & 7;
  const int xcd = blockIdx.x & 7, pos = blockIdx.x >> 3;
  const int swz = ((xcd < rr) ? xcd * (qq + 1) : rr * (qq + 1) + (xcd - rr) * qq) + pos;
  const int m0 = (swz / nn) * 128;
  const int n0 = (swz % nn) * 128;

  const int wm = (wave >> 1) * 64, wn = (wave & 1) * 64;
  const int lr = lane & 15;          // fragment row (A) / col (B)
  const int lg = lane >> 4;          // k-group 0..3 (8 ushorts each)

  // staging geometry: wave covers rows wave*32 .. wave*32+31 (4 issues of 8 rows)
  const int srow = wave * 32 + (lane >> 3);  // + i*8
  const int sslot = lane & 7;

  auto stage = [&](int buf, int k0) {
#pragma unroll
    for (int i = 0; i < 4; ++i) {
      const int row = srow + i * 8;
      const int ca = sslot ^ (row & 7);          // pre-swizzled source chunk
      gload16(A  + (size_t)(m0 + row) * K + k0 + ca * 8, &As[buf][(wave * 32 + i * 8) * 64]);
      gload16(Bt + (size_t)(n0 + row) * K + k0 + ca * 8, &Bs[buf][(wave * 32 + i * 8) * 64]);
    }
  };

  f32x4 acc[4][4] = {};

  stage(0, 0);
  __syncthreads();   // drain prologue staging
  int cur = 0;

  for (int k0 = 0; k0 < K; k0 += 64) {
    if (k0 + 64 < K) stage(cur ^ 1, k0 + 64);   // prefetch next tile (in flight over compute)

    bf16x8 af[2][4], bg[2][4];
#pragma unroll
    for (int kk = 0; kk < 2; ++kk) {
#pragma unroll
      for (int i = 0; i < 4; ++i) {
        int row = wm + i * 16 + lr;
        int slot = (kk * 4 + lg) ^ (row & 7);
        af[kk][i] = *(const bf16x8*)(&As[cur][row * 64 + slot * 8]);
        row = wn + i * 16 + lr;
        slot = (kk * 4 + lg) ^ (row & 7);
        bg[kk][i] = *(const bf16x8*)(&Bs[cur][row * 64 + slot * 8]);
      }
    }
#pragma unroll
    for (int kk = 0; kk < 2; ++kk)
#pragma unroll
      for (int i = 0; i < 4; ++i)
#pragma unroll
        for (int j = 0; j < 4; ++j)
          acc[i][j] = __builtin_amdgcn_mfma_f32_16x16x32_bf16(af[kk][i], bg[kk][j], acc[i][j], 0, 0, 0);

    __syncthreads();   // drains vmcnt (next-tile staging) + protects buffer swap
    cur ^= 1;
  }

  const int orow = lg * 4;
#pragma unroll
  for (int i = 0; i < 4; ++i) {
#pragma unroll
    for (int j = 0; j < 4; ++j) {
      const int n = n0 + wn + j * 16 + lr;
      if (n < N) {
#pragma unroll
        for (int r = 0; r < 4; ++r) {
          const int m = m0 + wm + i * 16 + orow + r;
          float v = acc[i][j][r] + bias[n];
          if (HAS_ADD) v += add[(size_t)m * N + n];
          out[(size_t)m * N + n] = v;
        }
      }
    }
  }
}

// ---------------- deformable sampling: softmax(attw) + bilinear gather + NP-sum
// grid = NB*LQT blocks, block = 192 threads: head = t>>5, 32 lanes x float4 over DH=128
__global__ __launch_bounds__(192) void deform_attn(const float* __restrict__ soaw,
                                                   const float* __restrict__ rp,
                                                   const float* __restrict__ value,
                                                   unsigned short* __restrict__ attn) {
  const int row = blockIdx.x;  // b*LQT + q
  const int b = row / LQT;
  const int t = threadIdx.x;
  const int h = t >> 5;
  const int l = t & 31;
  const float* sa = soaw + (size_t)row * 128;
  const float bx = rp[(size_t)row * 2 + 0] * (float)WW - 0.5f;
  const float by = rp[(size_t)row * 2 + 1] * (float)HH - 0.5f;

  // softmax over NP=4 attention logits of this head
  float lg0 = sa[48 + h * 4 + 0], lg1 = sa[48 + h * 4 + 1];
  float lg2 = sa[48 + h * 4 + 2], lg3 = sa[48 + h * 4 + 3];
  float mx = fmaxf(fmaxf(lg0, lg1), fmaxf(lg2, lg3));
  float e0 = expf(lg0 - mx), e1 = expf(lg1 - mx), e2 = expf(lg2 - mx), e3 = expf(lg3 - mx);
  float inv = 1.0f / (e0 + e1 + e2 + e3);
  float awp[4] = {e0 * inv, e1 * inv, e2 * inv, e3 * inv};

  const float* vb = value + (size_t)b * LINT * DIMC + h * DHD + l * 4;
  float ax = 0.f, ay = 0.f, az = 0.f, aw = 0.f;
#pragma unroll
  for (int p = 0; p < 4; ++p) {
    float fx = bx + sa[h * 8 + p * 2 + 0];
    float fy = by + sa[h * 8 + p * 2 + 1];
    float x0f = floorf(fx), y0f = floorf(fy);
    float wx = fx - x0f, wy = fy - y0f;
    int x0 = (int)x0f, y0 = (int)y0f;
#pragma unroll
    for (int dy = 0; dy < 2; ++dy) {
#pragma unroll
      for (int dx = 0; dx < 2; ++dx) {
        int xi = x0 + dx, yi = y0 + dy;
        float w = (dy ? wy : 1.f - wy) * (dx ? wx : 1.f - wx) * awp[p];
        if (xi < 0 || xi >= WW || yi < 0 || yi >= HH) w = 0.f;
        int xc = min(max(xi, 0), WW - 1), yc = min(max(yi, 0), HH - 1);
        const float4 g = *(const float4*)(vb + (size_t)(yc * WW + xc) * DIMC);
        ax += w * g.x; ay += w * g.y; az += w * g.z; aw += w * g.w;
      }
    }
  }
  unsigned short* op = attn + (size_t)row * DIMC + h * DHD + l * 4;
  ushort4 ov;
  ov.x = f2bf(ax); ov.y = f2bf(ay); ov.z = f2bf(az); ov.w = f2bf(aw);
  *(ushort4*)op = ov;
}

// ---------------- depthwise 3x3 conv (3 image scales) + exact GELU -> bf16
__global__ __launch_bounds__(192) void dwconv_gelu(const float* __restrict__ h1,
                                                   const float* __restrict__ dwW,
                                                   const float* __restrict__ dwb,
                                                   unsigned short* __restrict__ out) {
  const int blk = blockIdx.x;  // b*LQT + q
  const int b = blk / LQT;
  const int q = blk % LQT;
  int base, Wi, Hi;
  if (q < 9216)       { base = 0;     Wi = 96; Hi = 96; }
  else if (q < 11520) { base = 9216;  Wi = 48; Hi = 48; }
  else                { base = 11520; Wi = 24; Hi = 24; }
  const int loc = q - base;
  const int y = loc / Wi, x = loc % Wi;
  const int c = threadIdx.x;
  const float* src = h1 + ((size_t)b * LQT + base) * HIDC + c;
  float acc = dwb[c];
#pragma unroll
  for (int dy = -1; dy <= 1; ++dy) {
    int yy = y + dy;
    if (yy < 0 || yy >= Hi) continue;
#pragma unroll
    for (int dx = -1; dx <= 1; ++dx) {
      int xx = x + dx;
      if (xx < 0 || xx >= Wi) continue;
      acc += dwW[c * 9 + (dy + 1) * 3 + (dx + 1)] * src[(size_t)(yy * Wi + xx) * HIDC];
    }
  }
  float g = 0.5f * acc * (1.0f + erff(acc * 0.70710678118654752f));
  out[(size_t)blk * HIDC + c] = f2bf(g);
}

// ---------------- launch
extern "C" void kernel_launch(void* const* d_in, const int* in_sizes, int n_in,
                              void* d_out, int out_size, void* d_ws, size_t ws_size,
                              hipStream_t stream) {
  const float* query = (const float*)d_in[0];
  const float* rp    = (const float*)d_in[1];
  const float* feat  = (const float*)d_in[2];
  const float* qn_g  = (const float*)d_in[7];
  const float* qn_b  = (const float*)d_in[8];
  const float* fn_g  = (const float*)d_in[9];
  const float* fn_b  = (const float*)d_in[10];
  const float* mn_g  = (const float*)d_in[11];
  const float* mn_b  = (const float*)d_in[12];
  const float* vW    = (const float*)d_in[13];
  const float* vb    = (const float*)d_in[14];
  const float* soW   = (const float*)d_in[15];
  const float* sob   = (const float*)d_in[16];
  const float* awW   = (const float*)d_in[17];
  const float* awb   = (const float*)d_in[18];
  const float* opW   = (const float*)d_in[19];
  const float* opb   = (const float*)d_in[20];
  const float* fc1W  = (const float*)d_in[21];
  const float* fc1b  = (const float*)d_in[22];
  const float* dwW   = (const float*)d_in[23];
  const float* dwb   = (const float*)d_in[24];
  const float* fc2W  = (const float*)d_in[25];
  const float* fc2b  = (const float*)d_in[26];
  float* out = (float*)d_out;
  (void)in_sizes; (void)n_in; (void)out_size; (void)ws_size;

  char* ws = (char*)d_ws;
  size_t off = 0;
  auto alloc = [&](size_t bytes) -> void* {
    off = (off + 255) & ~(size_t)255;
    void* p = ws + off;
    off += bytes;
    return p;
  };

  const int MQ = NB * LQT;   // 24192
  const int MF = NB * LINT;  // 4608

  unsigned short* vWt    = (unsigned short*)alloc((size_t)768 * 768 * 2);
  unsigned short* opWt   = (unsigned short*)alloc((size_t)768 * 768 * 2);
  unsigned short* soawWt = (unsigned short*)alloc((size_t)128 * 768 * 2);
  unsigned short* fc1Wt  = (unsigned short*)alloc((size_t)256 * 768 * 2);
  unsigned short* fc2Wt  = (unsigned short*)alloc((size_t)768 * 192 * 2);
  float*          soawb  = (float*)alloc(128 * 4);
  unsigned short* f_ln   = (unsigned short*)alloc((size_t)MF * DIMC * 2);
  unsigned short* q_ln   = (unsigned short*)alloc((size_t)MQ * DIMC * 2);  // reused as ln(x)
  float*          value  = (float*)alloc((size_t)MF * DIMC * 4);
  float*          soaw   = (float*)alloc((size_t)MQ * 128 * 4);            // reused as conv out (bf16)
  unsigned short* attnb  = (unsigned short*)alloc((size_t)MQ * DIMC * 2);  // reused as h1 (fp32 fits)
  float*          xbuf   = (float*)alloc((size_t)MQ * DIMC * 4);

  float* h1 = (float*)attnb;
  unsigned short* coutb = (unsigned short*)soaw;
  unsigned short* lnx = q_ln;

  // weight packing (tiny)
  pack_wt<<<dim3((768 * 768 + 255) / 256), dim3(256), 0, stream>>>(vW, vWt, 768, 768, 768);
  pack_wt<<<dim3((768 * 768 + 255) / 256), dim3(256), 0, stream>>>(opW, opWt, 768, 768, 768);
  pack_wt<<<dim3((256 * 768 + 255) / 256), dim3(256), 0, stream>>>(fc1W, fc1Wt, 768, 192, 256);
  pack_wt<<<dim3((768 * 192 + 255) / 256), dim3(256), 0, stream>>>(fc2W, fc2Wt, 192, 768, 768);
  pack_soaw<<<dim3((128 * 768 + 255) / 256), dim3(256), 0, stream>>>(soW, awW, sob, awb, soawWt, soawb);

  // LayerNorms
  ln_to_bf16<<<dim3(MF), dim3(256), 0, stream>>>(feat, fn_g, fn_b, f_ln);
  ln_to_bf16<<<dim3(MQ), dim3(256), 0, stream>>>(query, qn_g, qn_b, q_ln);

  // value projection: [4608,768] = f_ln @ vW + vb
  gemm_bt<false><<<dim3((MF / 128) * 6), dim3(256), 0, stream>>>(f_ln, vWt, vb, nullptr, value, MF, 768, 768, 6);

  // sampling offsets + attn logits (fused, N=128 padded)
  gemm_bt<false><<<dim3(MQ / 128), dim3(256), 0, stream>>>(q_ln, soawWt, soawb, nullptr, soaw, MQ, 128, 768, 1);

  // deformable bilinear sampling -> attn operand (bf16)
  deform_attn<<<dim3(MQ), dim3(192), 0, stream>>>(soaw, rp, value, attnb);

  // output projection + residual: x = attn @ opW + opb + query
  gemm_bt<true><<<dim3((MQ / 128) * 6), dim3(256), 0, stream>>>(attnb, opWt, opb, query, xbuf, MQ, 768, 768, 6);

  // LN(x)
  ln_to_bf16<<<dim3(MQ), dim3(256), 0, stream>>>(xbuf, mn_g, mn_b, lnx);

  // fc1: [MQ,192] = lnx @ fc1W + fc1b
  gemm_bt<false><<<dim3((MQ / 128) * 2), dim3(256), 0, stream>>>(lnx, fc1Wt, fc1b, nullptr, h1, MQ, 192, 768, 2);

  // depthwise conv (3 scales) + GELU
  dwconv_gelu<<<dim3(MQ), dim3(192), 0, stream>>>(h1, dwW, dwb, coutb);

  // fc2 + residual: out = x + cout @ fc2W + fc2b
  gemm_bt<true><<<dim3((MQ / 128) * 6), dim3(256), 0, stream>>>(coutb, fc2Wt, fc2b, xbuf, out, MQ, 768, 192, 6);
}